// Round 8
// baseline (201.582 us; speedup 1.0000x reference)
//
#include <hip/hip_runtime.h>
#include <hip/hip_bf16.h>
#include <math.h>

#define BATCH 8
#define SQ 2048
#define SK 2048
#define DD 512
#define DV 512
#define RP 40   // LDS row pitch in shorts (80 B). Frag b128 reads are 2-way (free, m136);
                // the bank-conflict floor is structural -- do not chase (r4 evidence).

typedef short bf16x8_t __attribute__((ext_vector_type(8)));
typedef float f32x4_t __attribute__((ext_vector_type(4)));

// packed RTNE fp32x2 -> bf16x2 (v_cvt_pk_bf16_f32)
__device__ __forceinline__ unsigned int pk_bf16(float a, float b) {
    __hip_bfloat162 h = __float22bfloat162_rn(float2{a, b});
    unsigned int u;
    __builtin_memcpy(&u, &h, 4);
    return u;
}
__device__ __forceinline__ float from_hi(unsigned int u) {
    return __builtin_bit_cast(float, u);
}

// ---------------------------------------------------------------------------
// Kernel 1: fp32 partials of M^T = V^T K (un-scaled), t-split by 4.
// A-frags from V, B-frags from K -> accumulator tile is [v][d] directly.
// Mpart: [ts(4)][b(8)][v(512)][d(512)] fp32 == 32 MB, lives in d_out.
// (round-3 known-good form, verbatim)
// ---------------------------------------------------------------------------
__global__ __launch_bounds__(256) void ktv_mfma(const float* __restrict__ Kp,
                                                const float* __restrict__ Vp,
                                                float* __restrict__ Mpart) {
    const int b  = blockIdx.z & 7;
    const int ts = blockIdx.z >> 3;
    const int d0 = blockIdx.x * 128;
    const int v0 = blockIdx.y * 128;
    const float* Kb = Kp + (size_t)b * SK * DD;
    const float* Vb = Vp + (size_t)b * SK * DV;

    __shared__ __align__(16) unsigned short Kh[128 * RP], Kl[128 * RP],
                                            Vh[128 * RP], Vl[128 * RP];

    const int tid  = threadIdx.x;
    const int lane = tid & 63;
    const int w    = tid >> 6;
    const int wv   = (w & 1) * 64;    // A-side: v rows
    const int wd   = (w >> 1) * 64;   // B-side: d rows
    const int uu   = tid >> 5;   // 0..7  (t-pair selector)
    const int xx   = tid & 31;   // d/v column selector

    f32x4_t acc[4][4];
#pragma unroll
    for (int i = 0; i < 4; ++i)
#pragma unroll
        for (int j = 0; j < 4; ++j) acc[i][j] = (f32x4_t){0.f, 0.f, 0.f, 0.f};

    const int tb = ts * 512;

    float kr0[2][4], kr1[2][4], vr0[2][4], vr1[2][4];
    auto load_tile = [&](int t0l) {
#pragma unroll
        for (int p = 0; p < 2; ++p) {
            const int t = 16 * p + 2 * uu;
            const size_t gr = (size_t)(tb + t0l + t);
#pragma unroll
            for (int c = 0; c < 4; ++c) {
                const int d = xx + 32 * c;
                kr0[p][c] = Kb[gr * DD + d0 + d];
                kr1[p][c] = Kb[(gr + 1) * DD + d0 + d];
                vr0[p][c] = Vb[gr * DV + v0 + d];
                vr1[p][c] = Vb[(gr + 1) * DV + v0 + d];
            }
        }
    };

    load_tile(0);
    for (int t0 = 0; t0 < 512; t0 += 32) {
#pragma unroll
        for (int p = 0; p < 2; ++p) {
            const int t  = 16 * p + 2 * uu;
            const int to = (t >> 3) * 8 + (t & 7);
#pragma unroll
            for (int c = 0; c < 4; ++c) {
                const int d   = xx + 32 * c;
                const int off = d * RP + to;
                {
                    const unsigned int h = pk_bf16(kr0[p][c], kr1[p][c]);
                    const float r0 = kr0[p][c] - from_hi(h << 16);
                    const float r1 = kr1[p][c] - from_hi(h & 0xFFFF0000u);
                    *(unsigned int*)(Kh + off) = h;
                    *(unsigned int*)(Kl + off) = pk_bf16(r0, r1);
                }
                {
                    const unsigned int h = pk_bf16(vr0[p][c], vr1[p][c]);
                    const float r0 = vr0[p][c] - from_hi(h << 16);
                    const float r1 = vr1[p][c] - from_hi(h & 0xFFFF0000u);
                    *(unsigned int*)(Vh + off) = h;
                    *(unsigned int*)(Vl + off) = pk_bf16(r0, r1);
                }
            }
        }
        __syncthreads();

        if (t0 + 32 < 512) load_tile(t0 + 32);

        const int kq = lane >> 4;
        const int mr = lane & 15;
        bf16x8_t ah[4], al_[4];
#pragma unroll
        for (int tm = 0; tm < 4; ++tm) {
            const int off = (wv + tm * 16 + mr) * RP + kq * 8;
            ah[tm]  = *(const bf16x8_t*)(Vh + off);
            al_[tm] = *(const bf16x8_t*)(Vl + off);
        }
#pragma unroll
        for (int tn = 0; tn < 4; ++tn) {
            const int off = (wd + tn * 16 + mr) * RP + kq * 8;
            const bf16x8_t bh = *(const bf16x8_t*)(Kh + off);
            const bf16x8_t bl = *(const bf16x8_t*)(Kl + off);
#pragma unroll
            for (int tm = 0; tm < 4; ++tm) {
                acc[tm][tn] = __builtin_amdgcn_mfma_f32_16x16x32_bf16(ah[tm], bh, acc[tm][tn], 0, 0, 0);
                acc[tm][tn] = __builtin_amdgcn_mfma_f32_16x16x32_bf16(ah[tm], bl, acc[tm][tn], 0, 0, 0);
                acc[tm][tn] = __builtin_amdgcn_mfma_f32_16x16x32_bf16(al_[tm], bh, acc[tm][tn], 0, 0, 0);
            }
        }
        __syncthreads();
    }

    float* Mp = Mpart + (size_t)(ts * 8 + b) * DV * DD;
    const int quad = lane >> 4;
    const int col  = lane & 15;
#pragma unroll
    for (int tm = 0; tm < 4; ++tm)
#pragma unroll
        for (int tn = 0; tn < 4; ++tn)
#pragma unroll
            for (int r = 0; r < 4; ++r) {
                const int v = v0 + wv + tm * 16 + quad * 4 + r;
                const int d = d0 + wd + tn * 16 + col;
                Mp[(size_t)v * DD + d] = acc[tm][tn][r];
            }
}

// ---------------------------------------------------------------------------
// Kernel 2: pure streaming reduce (round-3 form, verbatim).
// ---------------------------------------------------------------------------
__global__ __launch_bounds__(256) void reduce_cvt(const float* __restrict__ Mpart,
                                                  unsigned short* __restrict__ Mth,
                                                  unsigned short* __restrict__ Mtl) {
    const size_t N  = (size_t)BATCH * DD * DV;
    const size_t i4 = ((size_t)blockIdx.x * 256 + threadIdx.x) * 4;

    float sx = 0.f, sy = 0.f, sz = 0.f, sw = 0.f;
#pragma unroll
    for (int sl = 0; sl < 4; ++sl) {
        const float4 f = *(const float4*)&Mpart[sl * N + i4];
        sx += f.x; sy += f.y; sz += f.z; sw += f.w;
    }

    const float s = 0.04419417382415922f;  // 1/sqrt(512)
    const float m0 = sx * s, m1 = sy * s, m2 = sz * s, m3 = sw * s;
    const unsigned int h0 = pk_bf16(m0, m1);
    const unsigned int h1 = pk_bf16(m2, m3);
    const float r0 = m0 - from_hi(h0 << 16);
    const float r1 = m1 - from_hi(h0 & 0xFFFF0000u);
    const float r2 = m2 - from_hi(h1 << 16);
    const float r3 = m3 - from_hi(h1 & 0xFFFF0000u);
    *(uint2*)&Mth[i4] = make_uint2(h0, h1);
    *(uint2*)&Mtl[i4] = make_uint2(pk_bf16(r0, r1), pk_bf16(r2, r3));
}

// ---------------------------------------------------------------------------
// Kernel 3: X = Q @ M with the masked softmax FUSED into the epilogue.
// Tile: 64 q-rows x FULL 512 v per block so each block owns complete rows.
// 512 threads = 8 waves; wave w computes the 64-v chunk [64w, 64w+64).
// Same BK=32, 3-term split MFMA, distance-1 prefetch, plain __syncthreads.
// LDS: Q(64 rows) + B(512 rows) hi/lo at pitch RP = ~94 KB -> 1 block/CU,
// 2 waves/SIMD (same wave depth as the proven r0 qm).
// Epilogue: mask -> per-wave shuffle row-max -> LDS cross-wave combine ->
// exp/sum (same path) -> normalized write. Deletes the softmax kernel and
// its 64 MB of traffic.
// ---------------------------------------------------------------------------
__global__ __launch_bounds__(512) void qmsm(const float* __restrict__ Qp,
                                            const unsigned short* __restrict__ Mth,
                                            const unsigned short* __restrict__ Mtl,
                                            const int* __restrict__ vlen,
                                            float* __restrict__ Xp) {
    const int b  = blockIdx.z;
    const int q0 = blockIdx.x * 64;
    const float* Qb = Qp + (size_t)b * SQ * DD;
    const unsigned short* Bhg = Mth + (size_t)b * DV * DD;
    const unsigned short* Blg = Mtl + (size_t)b * DV * DD;

    __shared__ __align__(16) unsigned short Qh[64 * RP], Ql[64 * RP],
                                            Bh[512 * RP], Bl[512 * RP];
    __shared__ float red_m[8][64], red_s[8][64];
    __shared__ int vls[64];

    const int tid  = threadIdx.x;
    const int lane = tid & 63;
    const int w    = tid >> 6;        // 0..7: v-chunk owner

    if (tid < 64) vls[tid] = vlen[q0 + tid];

    f32x4_t acc[4][4];
#pragma unroll
    for (int i = 0; i < 4; ++i)
#pragma unroll
        for (int j = 0; j < 4; ++j) acc[i][j] = (f32x4_t){0.f, 0.f, 0.f, 0.f};

    // staging ownership
    const int qrow = tid >> 3;          // 0..63
    const int qdc  = (tid & 7) * 4;     // 0..28
    const int br   = tid >> 2;          // 0..127 (B row base, 4 passes of 128)
    const int bkq  = tid & 3;           // 0..3

    float4 pq;
    bf16x8_t pbh[4], pbl[4];
    auto load_tile = [&](int k0l) {
        pq = *(const float4*)&Qb[(size_t)(q0 + qrow) * DD + k0l + qdc];
#pragma unroll
        for (int p = 0; p < 4; ++p) {
            const size_t go = (size_t)(p * 128 + br) * DD + k0l + bkq * 8;
            pbh[p] = *(const bf16x8_t*)&Bhg[go];
            pbl[p] = *(const bf16x8_t*)&Blg[go];
        }
    };

    load_tile(0);
    for (int k0 = 0; k0 < DD; k0 += 32) {
        // ---- stage Q (cvt+split) and B (straight copy) from regs ----
        {
            const float4 f = pq;
            const unsigned int h01 = pk_bf16(f.x, f.y);
            const unsigned int h23 = pk_bf16(f.z, f.w);
            const float r0 = f.x - from_hi(h01 << 16);
            const float r1 = f.y - from_hi(h01 & 0xFFFF0000u);
            const float r2 = f.z - from_hi(h23 << 16);
            const float r3 = f.w - from_hi(h23 & 0xFFFF0000u);
            const int off = qrow * RP + qdc;
            *(uint2*)(Qh + off) = make_uint2(h01, h23);
            *(uint2*)(Ql + off) = make_uint2(pk_bf16(r0, r1), pk_bf16(r2, r3));
        }
#pragma unroll
        for (int p = 0; p < 4; ++p) {
            const int off = (p * 128 + br) * RP + bkq * 8;
            *(bf16x8_t*)(Bh + off) = pbh[p];
            *(bf16x8_t*)(Bl + off) = pbl[p];
        }
        __syncthreads();

        if (k0 + 32 < DD) load_tile(k0 + 32);

        const int kq = lane >> 4;
        const int mr = lane & 15;
        bf16x8_t ah[4], al_[4];
#pragma unroll
        for (int tm = 0; tm < 4; ++tm) {
            const int off = (tm * 16 + mr) * RP + kq * 8;
            ah[tm]  = *(const bf16x8_t*)(Qh + off);
            al_[tm] = *(const bf16x8_t*)(Ql + off);
        }
#pragma unroll
        for (int tn = 0; tn < 4; ++tn) {
            const int off = (w * 64 + tn * 16 + mr) * RP + kq * 8;
            const bf16x8_t bh = *(const bf16x8_t*)(Bh + off);
            const bf16x8_t bl = *(const bf16x8_t*)(Bl + off);
#pragma unroll
            for (int tm = 0; tm < 4; ++tm) {
                acc[tm][tn] = __builtin_amdgcn_mfma_f32_16x16x32_bf16(ah[tm], bh, acc[tm][tn], 0, 0, 0);
                acc[tm][tn] = __builtin_amdgcn_mfma_f32_16x16x32_bf16(ah[tm], bl, acc[tm][tn], 0, 0, 0);
                acc[tm][tn] = __builtin_amdgcn_mfma_f32_16x16x32_bf16(al_[tm], bh, acc[tm][tn], 0, 0, 0);
            }
        }
        __syncthreads();
    }

    // ================= fused masked softmax epilogue =================
    const int quad = lane >> 4;
    const int col  = lane & 15;

    // 1) mask in-register (v > vl -> -1e6, matching the old softmax kernel)
#pragma unroll
    for (int tm = 0; tm < 4; ++tm)
#pragma unroll
        for (int r = 0; r < 4; ++r) {
            const int vl = vls[tm * 16 + quad * 4 + r];
#pragma unroll
            for (int tn = 0; tn < 4; ++tn) {
                const int v = w * 64 + tn * 16 + col;
                if (v > vl) acc[tm][tn][r] = -1.0e6f;
            }
        }

    // 2) per-wave row max over this wave's 64 cols (in-lane over tn, then
    //    shuffle over the 16-lane col group; xor of bits 0..3 stays in-group)
    float pm[4][4];
#pragma unroll
    for (int tm = 0; tm < 4; ++tm)
#pragma unroll
        for (int r = 0; r < 4; ++r) {
            float m = acc[tm][0][r];
#pragma unroll
            for (int tn = 1; tn < 4; ++tn) m = fmaxf(m, acc[tm][tn][r]);
#pragma unroll
            for (int off = 1; off < 16; off <<= 1) m = fmaxf(m, __shfl_xor(m, off, 64));
            pm[tm][r] = m;
        }
    if (col == 0) {
#pragma unroll
        for (int tm = 0; tm < 4; ++tm)
#pragma unroll
            for (int r = 0; r < 4; ++r)
                red_m[w][tm * 16 + quad * 4 + r] = pm[tm][r];
    }
    __syncthreads();

    // 3) cross-wave max combine
    float rm[4][4];
#pragma unroll
    for (int tm = 0; tm < 4; ++tm)
#pragma unroll
        for (int r = 0; r < 4; ++r) {
            const int row = tm * 16 + quad * 4 + r;
            float m = red_m[0][row];
#pragma unroll
            for (int w2 = 1; w2 < 8; ++w2) m = fmaxf(m, red_m[w2][row]);
            rm[tm][r] = m;
        }

    // 4) exp + per-wave partial sum
#pragma unroll
    for (int tm = 0; tm < 4; ++tm)
#pragma unroll
        for (int r = 0; r < 4; ++r) {
            float s = 0.f;
#pragma unroll
            for (int tn = 0; tn < 4; ++tn) {
                const float p = __expf(acc[tm][tn][r] - rm[tm][r]);
                acc[tm][tn][r] = p;
                s += p;
            }
#pragma unroll
            for (int off = 1; off < 16; off <<= 1) s += __shfl_xor(s, off, 64);
            pm[tm][r] = s;   // reuse pm as partial-sum register
        }
    if (col == 0) {
#pragma unroll
        for (int tm = 0; tm < 4; ++tm)
#pragma unroll
            for (int r = 0; r < 4; ++r)
                red_s[w][tm * 16 + quad * 4 + r] = pm[tm][r];
    }
    __syncthreads();

    // 5) cross-wave sum combine + normalized write
    float* Xb = Xp + (size_t)b * SQ * DV;
#pragma unroll
    for (int tm = 0; tm < 4; ++tm)
#pragma unroll
        for (int r = 0; r < 4; ++r) {
            const int row = tm * 16 + quad * 4 + r;
            float s = red_s[0][row];
#pragma unroll
            for (int w2 = 1; w2 < 8; ++w2) s += red_s[w2][row];
            const float inv = 1.0f / s;
#pragma unroll
            for (int tn = 0; tn < 4; ++tn)
                Xb[(size_t)(q0 + row) * DV + w * 64 + tn * 16 + col] = acc[tm][tn][r] * inv;
        }
}

extern "C" void kernel_launch(void* const* d_in, const int* in_sizes, int n_in,
                              void* d_out, int out_size, void* d_ws, size_t ws_size,
                              hipStream_t stream) {
    const float* Kp   = (const float*)d_in[0];
    const float* Vp   = (const float*)d_in[1];
    const float* Qp   = (const float*)d_in[2];
    const int*   vlen = (const int*)d_in[3];
    float* out = (float*)d_out;

    // ws: Mt_hi (4 MB) | Mt_lo (4 MB) -- proven-safe 8 MB footprint.
    unsigned short* Mth = (unsigned short*)d_ws;
    unsigned short* Mtl = Mth + (size_t)BATCH * DD * DV;
    // fp32 partials (4 x 8 MB = 32 MB) live in d_out; overwritten by qmsm later.
    float* Mpart = out;

    ktv_mfma<<<dim3(4, 4, 32), 256, 0, stream>>>(Kp, Vp, Mpart);
    reduce_cvt<<<dim3(2048), 256, 0, stream>>>(Mpart, Mth, Mtl);
    qmsm<<<dim3(32, 1, 8), 512, 0, stream>>>(Qp, Mth, Mtl, vlen, out);
}

// Round 9
// 196.027 us; speedup vs baseline: 1.0283x; 1.0283x over previous
//
#include <hip/hip_runtime.h>
#include <hip/hip_bf16.h>
#include <math.h>

#define BATCH 8
#define SQ 2048
#define SK 2048
#define DD 512
#define DV 512
#define RP 40   // LDS row pitch in shorts (80 B). Aggregate frag-read bank spread is
                // uniform; the conflict floor is structural -- do not chase (r4).

typedef short bf16x8_t __attribute__((ext_vector_type(8)));
typedef float f32x4_t __attribute__((ext_vector_type(4)));

// packed RTNE fp32x2 -> bf16x2 (v_cvt_pk_bf16_f32)
__device__ __forceinline__ unsigned int pk_bf16(float a, float b) {
    __hip_bfloat162 h = __float22bfloat162_rn(float2{a, b});
    unsigned int u;
    __builtin_memcpy(&u, &h, 4);
    return u;
}
__device__ __forceinline__ float from_hi(unsigned int u) {
    return __builtin_bit_cast(float, u);
}

// ---------------------------------------------------------------------------
// Kernel 1: fp32 partials of M^T = V^T K (un-scaled), t-split by 4.
// A-frags from V, B-frags from K -> accumulator tile is [v][d] directly.
// Mpart: [ts(4)][b(8)][v(512)][d(512)] fp32 == 32 MB, lives in d_out.
// Round-9 change (ISOLATED): MFMA term-reorder. The old (tn,tm,term) order
// emitted each (tm,tn)'s 3 split-term MFMAs back-to-back chained through the
// same acc -- in-order issue stalls ~2x latency per chain with only 2
// waves/SIMD to cover. New (term,tn,tm) order: 16 independent MFMAs per
// term, acc re-use distance >= 16 >= latency. Per-acc term order hh->hl->lh
// is preserved -> bit-identical accumulation. Everything else r3-verbatim.
// ---------------------------------------------------------------------------
__global__ __launch_bounds__(256) void ktv_mfma(const float* __restrict__ Kp,
                                                const float* __restrict__ Vp,
                                                float* __restrict__ Mpart) {
    const int b  = blockIdx.z & 7;
    const int ts = blockIdx.z >> 3;
    const int d0 = blockIdx.x * 128;
    const int v0 = blockIdx.y * 128;
    const float* Kb = Kp + (size_t)b * SK * DD;
    const float* Vb = Vp + (size_t)b * SK * DV;

    __shared__ __align__(16) unsigned short Kh[128 * RP], Kl[128 * RP],
                                            Vh[128 * RP], Vl[128 * RP];

    const int tid  = threadIdx.x;
    const int lane = tid & 63;
    const int w    = tid >> 6;
    const int wv   = (w & 1) * 64;    // A-side: v rows
    const int wd   = (w >> 1) * 64;   // B-side: d rows
    const int uu   = tid >> 5;   // 0..7  (t-pair selector)
    const int xx   = tid & 31;   // d/v column selector

    f32x4_t acc[4][4];
#pragma unroll
    for (int i = 0; i < 4; ++i)
#pragma unroll
        for (int j = 0; j < 4; ++j) acc[i][j] = (f32x4_t){0.f, 0.f, 0.f, 0.f};

    const int tb = ts * 512;

    float kr0[2][4], kr1[2][4], vr0[2][4], vr1[2][4];
    auto load_tile = [&](int t0l) {
#pragma unroll
        for (int p = 0; p < 2; ++p) {
            const int t = 16 * p + 2 * uu;
            const size_t gr = (size_t)(tb + t0l + t);
#pragma unroll
            for (int c = 0; c < 4; ++c) {
                const int d = xx + 32 * c;
                kr0[p][c] = Kb[gr * DD + d0 + d];
                kr1[p][c] = Kb[(gr + 1) * DD + d0 + d];
                vr0[p][c] = Vb[gr * DV + v0 + d];
                vr1[p][c] = Vb[(gr + 1) * DV + v0 + d];
            }
        }
    };

    load_tile(0);
    for (int t0 = 0; t0 < 512; t0 += 32) {
#pragma unroll
        for (int p = 0; p < 2; ++p) {
            const int t  = 16 * p + 2 * uu;
            const int to = (t >> 3) * 8 + (t & 7);
#pragma unroll
            for (int c = 0; c < 4; ++c) {
                const int d   = xx + 32 * c;
                const int off = d * RP + to;
                {
                    const unsigned int h = pk_bf16(kr0[p][c], kr1[p][c]);
                    const float r0 = kr0[p][c] - from_hi(h << 16);
                    const float r1 = kr1[p][c] - from_hi(h & 0xFFFF0000u);
                    *(unsigned int*)(Kh + off) = h;
                    *(unsigned int*)(Kl + off) = pk_bf16(r0, r1);
                }
                {
                    const unsigned int h = pk_bf16(vr0[p][c], vr1[p][c]);
                    const float r0 = vr0[p][c] - from_hi(h << 16);
                    const float r1 = vr1[p][c] - from_hi(h & 0xFFFF0000u);
                    *(unsigned int*)(Vh + off) = h;
                    *(unsigned int*)(Vl + off) = pk_bf16(r0, r1);
                }
            }
        }
        __syncthreads();

        if (t0 + 32 < 512) load_tile(t0 + 32);

        // ---- MFMA (A = V rows, B = K rows), term-reordered ----
        const int kq = lane >> 4;
        const int mr = lane & 15;
        bf16x8_t ah[4], al_[4], bh[4], bl[4];
#pragma unroll
        for (int tm = 0; tm < 4; ++tm) {
            const int off = (wv + tm * 16 + mr) * RP + kq * 8;
            ah[tm]  = *(const bf16x8_t*)(Vh + off);
            al_[tm] = *(const bf16x8_t*)(Vl + off);
        }
#pragma unroll
        for (int tn = 0; tn < 4; ++tn) {
            const int off = (wd + tn * 16 + mr) * RP + kq * 8;
            bh[tn] = *(const bf16x8_t*)(Kh + off);
            bl[tn] = *(const bf16x8_t*)(Kl + off);
        }
        // term 1: Vh * Kh   (16 independent MFMAs)
#pragma unroll
        for (int tn = 0; tn < 4; ++tn)
#pragma unroll
            for (int tm = 0; tm < 4; ++tm)
                acc[tm][tn] = __builtin_amdgcn_mfma_f32_16x16x32_bf16(ah[tm], bh[tn], acc[tm][tn], 0, 0, 0);
        // term 2: Vh * Kl
#pragma unroll
        for (int tn = 0; tn < 4; ++tn)
#pragma unroll
            for (int tm = 0; tm < 4; ++tm)
                acc[tm][tn] = __builtin_amdgcn_mfma_f32_16x16x32_bf16(ah[tm], bl[tn], acc[tm][tn], 0, 0, 0);
        // term 3: Vl * Kh
#pragma unroll
        for (int tn = 0; tn < 4; ++tn)
#pragma unroll
            for (int tm = 0; tm < 4; ++tm)
                acc[tm][tn] = __builtin_amdgcn_mfma_f32_16x16x32_bf16(al_[tm], bh[tn], acc[tm][tn], 0, 0, 0);
        __syncthreads();
    }

    float* Mp = Mpart + (size_t)(ts * 8 + b) * DV * DD;
    const int quad = lane >> 4;
    const int col  = lane & 15;
#pragma unroll
    for (int tm = 0; tm < 4; ++tm)
#pragma unroll
        for (int tn = 0; tn < 4; ++tn)
#pragma unroll
            for (int r = 0; r < 4; ++r) {
                const int v = v0 + wv + tm * 16 + quad * 4 + r;
                const int d = d0 + wd + tn * 16 + col;
                Mp[(size_t)v * DD + d] = acc[tm][tn][r];
            }
}

// ---------------------------------------------------------------------------
// Kernel 2: pure streaming reduce (round-3 form, verbatim).
// ---------------------------------------------------------------------------
__global__ __launch_bounds__(256) void reduce_cvt(const float* __restrict__ Mpart,
                                                  unsigned short* __restrict__ Mth,
                                                  unsigned short* __restrict__ Mtl) {
    const size_t N  = (size_t)BATCH * DD * DV;
    const size_t i4 = ((size_t)blockIdx.x * 256 + threadIdx.x) * 4;

    float sx = 0.f, sy = 0.f, sz = 0.f, sw = 0.f;
#pragma unroll
    for (int sl = 0; sl < 4; ++sl) {
        const float4 f = *(const float4*)&Mpart[sl * N + i4];
        sx += f.x; sy += f.y; sz += f.z; sw += f.w;
    }

    const float s = 0.04419417382415922f;  // 1/sqrt(512)
    const float m0 = sx * s, m1 = sy * s, m2 = sz * s, m3 = sw * s;
    const unsigned int h0 = pk_bf16(m0, m1);
    const unsigned int h1 = pk_bf16(m2, m3);
    const float r0 = m0 - from_hi(h0 << 16);
    const float r1 = m1 - from_hi(h0 & 0xFFFF0000u);
    const float r2 = m2 - from_hi(h1 << 16);
    const float r3 = m3 - from_hi(h1 & 0xFFFF0000u);
    *(uint2*)&Mth[i4] = make_uint2(h0, h1);
    *(uint2*)&Mtl[i4] = make_uint2(pk_bf16(r0, r1), pk_bf16(r2, r3));
}

// ---------------------------------------------------------------------------
// Kernel 3: X[b] = Q[b] @ M[b] via 3-term split MFMA. B pre-split bf16
// k-contiguous from ws; Q converted on the fly. 128x128 tiles, BK=32,
// register-prefetch pipeline. Round-9: same MFMA term-reorder as ktv;
// otherwise round-0 known-good form.
// ---------------------------------------------------------------------------
__global__ __launch_bounds__(256) void qm_mfma(const float* __restrict__ Qp,
                                               const unsigned short* __restrict__ Mth,
                                               const unsigned short* __restrict__ Mtl,
                                               float* __restrict__ Xp) {
    const int b  = blockIdx.z;
    const int q0 = blockIdx.x * 128;
    const int v0 = blockIdx.y * 128;
    const float* Qb = Qp + (size_t)b * SQ * DD;
    const unsigned short* Bhg = Mth + (size_t)b * DV * DD;
    const unsigned short* Blg = Mtl + (size_t)b * DV * DD;

    __shared__ __align__(16) unsigned short Qh[128 * RP], Ql[128 * RP],
                                            Bh[128 * RP], Bl[128 * RP];

    const int tid  = threadIdx.x;
    const int lane = tid & 63;
    const int w    = tid >> 6;
    const int wq   = (w & 1) * 64;
    const int wv   = (w >> 1) * 64;

    f32x4_t acc[4][4];
#pragma unroll
    for (int i = 0; i < 4; ++i)
#pragma unroll
        for (int j = 0; j < 4; ++j) acc[i][j] = (f32x4_t){0.f, 0.f, 0.f, 0.f};

    float4 pq[4];
    bf16x8_t pbh[2], pbl[2];
    const int qrow = tid >> 3;          // 0..31
    const int qdc  = (tid & 7) * 4;     // 0..28
    const int brow = tid >> 2;          // 0..63
    const int bkq  = tid & 3;           // 0..3
    auto load_tile = [&](int k0l) {
#pragma unroll
        for (int p = 0; p < 4; ++p)
            pq[p] = *(const float4*)&Qb[(size_t)(q0 + p * 32 + qrow) * DD + k0l + qdc];
#pragma unroll
        for (int p = 0; p < 2; ++p) {
            const size_t go = (size_t)(v0 + p * 64 + brow) * DD + k0l + bkq * 8;
            pbh[p] = *(const bf16x8_t*)&Bhg[go];
            pbl[p] = *(const bf16x8_t*)&Blg[go];
        }
    };

    load_tile(0);
    for (int k0 = 0; k0 < DD; k0 += 32) {
#pragma unroll
        for (int p = 0; p < 4; ++p) {
            const float4 f = pq[p];
            const unsigned int h01 = pk_bf16(f.x, f.y);
            const unsigned int h23 = pk_bf16(f.z, f.w);
            const float r0 = f.x - from_hi(h01 << 16);
            const float r1 = f.y - from_hi(h01 & 0xFFFF0000u);
            const float r2 = f.z - from_hi(h23 << 16);
            const float r3 = f.w - from_hi(h23 & 0xFFFF0000u);
            const int off = (p * 32 + qrow) * RP + qdc;
            *(uint2*)(Qh + off) = make_uint2(h01, h23);
            *(uint2*)(Ql + off) = make_uint2(pk_bf16(r0, r1), pk_bf16(r2, r3));
        }
#pragma unroll
        for (int p = 0; p < 2; ++p) {
            const int off = (p * 64 + brow) * RP + bkq * 8;
            *(bf16x8_t*)(Bh + off) = pbh[p];
            *(bf16x8_t*)(Bl + off) = pbl[p];
        }
        __syncthreads();

        if (k0 + 32 < DD) load_tile(k0 + 32);

        const int kq = lane >> 4;
        const int mr = lane & 15;
        bf16x8_t ah[4], al_[4], vbh[4], vbl[4];
#pragma unroll
        for (int tm = 0; tm < 4; ++tm) {
            const int off = (wq + tm * 16 + mr) * RP + kq * 8;
            ah[tm]  = *(const bf16x8_t*)(Qh + off);
            al_[tm] = *(const bf16x8_t*)(Ql + off);
        }
#pragma unroll
        for (int tn = 0; tn < 4; ++tn) {
            const int off = (wv + tn * 16 + mr) * RP + kq * 8;
            vbh[tn] = *(const bf16x8_t*)(Bh + off);
            vbl[tn] = *(const bf16x8_t*)(Bl + off);
        }
        // term 1: Qh * Bh
#pragma unroll
        for (int tn = 0; tn < 4; ++tn)
#pragma unroll
            for (int tm = 0; tm < 4; ++tm)
                acc[tm][tn] = __builtin_amdgcn_mfma_f32_16x16x32_bf16(ah[tm], vbh[tn], acc[tm][tn], 0, 0, 0);
        // term 2: Qh * Bl
#pragma unroll
        for (int tn = 0; tn < 4; ++tn)
#pragma unroll
            for (int tm = 0; tm < 4; ++tm)
                acc[tm][tn] = __builtin_amdgcn_mfma_f32_16x16x32_bf16(ah[tm], vbl[tn], acc[tm][tn], 0, 0, 0);
        // term 3: Ql * Bh
#pragma unroll
        for (int tn = 0; tn < 4; ++tn)
#pragma unroll
            for (int tm = 0; tm < 4; ++tm)
                acc[tm][tn] = __builtin_amdgcn_mfma_f32_16x16x32_bf16(al_[tm], vbh[tn], acc[tm][tn], 0, 0, 0);
        __syncthreads();
    }

    float* Xb = Xp + (size_t)b * SQ * DV;
    const int quad = lane >> 4;
    const int col  = lane & 15;
#pragma unroll
    for (int tm = 0; tm < 4; ++tm)
#pragma unroll
        for (int tn = 0; tn < 4; ++tn)
#pragma unroll
            for (int r = 0; r < 4; ++r)
                Xb[(size_t)(q0 + wq + tm * 16 + quad * 4 + r) * DV + v0 + wv + tn * 16 + col] = acc[tm][tn][r];
}

// ---------------------------------------------------------------------------
// Kernel 4: in-place masked softmax over last dim (512). One wave per row.
// (round-3 form, verbatim)
// ---------------------------------------------------------------------------
__global__ __launch_bounds__(256) void softmax_kernel(float* __restrict__ X,
                                                      const int* __restrict__ vlen) {
    const int wave = threadIdx.x >> 6;
    const int lane = threadIdx.x & 63;
    const int row  = blockIdx.x * 4 + wave;
    const int q    = row & (SQ - 1);
    float* xr = X + (size_t)row * DV;
    const int vl = vlen[q];

    float v[8];
#pragma unroll
    for (int u = 0; u < 2; ++u) {
        const int j0 = u * 256 + lane * 4;
        const float4 f = *(const float4*)&xr[j0];
        v[u * 4 + 0] = (j0 + 0 > vl) ? -1.0e6f : f.x;
        v[u * 4 + 1] = (j0 + 1 > vl) ? -1.0e6f : f.y;
        v[u * 4 + 2] = (j0 + 2 > vl) ? -1.0e6f : f.z;
        v[u * 4 + 3] = (j0 + 3 > vl) ? -1.0e6f : f.w;
    }

    float m = v[0];
#pragma unroll
    for (int i = 1; i < 8; ++i) m = fmaxf(m, v[i]);
#pragma unroll
    for (int off = 32; off > 0; off >>= 1) m = fmaxf(m, __shfl_xor(m, off, 64));

    float ssum = 0.f;
#pragma unroll
    for (int i = 0; i < 8; ++i) {
        v[i] = __expf(v[i] - m);
        ssum += v[i];
    }
#pragma unroll
    for (int off = 32; off > 0; off >>= 1) ssum += __shfl_xor(ssum, off, 64);

    const float inv = 1.0f / ssum;
#pragma unroll
    for (int u = 0; u < 2; ++u) {
        const int j0 = u * 256 + lane * 4;
        float4 o;
        o.x = v[u * 4 + 0] * inv;
        o.y = v[u * 4 + 1] * inv;
        o.z = v[u * 4 + 2] * inv;
        o.w = v[u * 4 + 3] * inv;
        *(float4*)&xr[j0] = o;
    }
}

extern "C" void kernel_launch(void* const* d_in, const int* in_sizes, int n_in,
                              void* d_out, int out_size, void* d_ws, size_t ws_size,
                              hipStream_t stream) {
    const float* Kp   = (const float*)d_in[0];
    const float* Vp   = (const float*)d_in[1];
    const float* Qp   = (const float*)d_in[2];
    const int*   vlen = (const int*)d_in[3];
    float* out = (float*)d_out;

    // ws: Mt_hi (4 MB) | Mt_lo (4 MB) -- proven-safe 8 MB footprint.
    unsigned short* Mth = (unsigned short*)d_ws;
    unsigned short* Mtl = Mth + (size_t)BATCH * DD * DV;
    // fp32 partials (4 x 8 MB = 32 MB) live in d_out; overwritten by qm later.
    float* Mpart = out;

    ktv_mfma<<<dim3(4, 4, 32), 256, 0, stream>>>(Kp, Vp, Mpart);
    reduce_cvt<<<dim3(2048), 256, 0, stream>>>(Mpart, Mth, Mtl);
    qm_mfma<<<dim3(16, 4, 8), 256, 0, stream>>>(Qp, Mth, Mtl, out);
    softmax_kernel<<<dim3(BATCH * SQ / 4), 256, 0, stream>>>(out, vlen);
}